// Round 7
// baseline (461.796 us; speedup 1.0000x reference)
//
#include <hip/hip_runtime.h>
#include <hip/hip_bf16.h>

#define B_   4
#define LQ_  4096
#define LS_  4096
#define DH_  1024
#define BQ_  64
#define BS_  256
#define NT_  (LS_/BS_)   /* 16 */
#define NTH  512

typedef __bf16 bf16x8 __attribute__((ext_vector_type(8)));
typedef float  f32x4  __attribute__((ext_vector_type(4)));
typedef float  f32x16 __attribute__((ext_vector_type(16)));
typedef unsigned char u8;

#define WAITL()  asm volatile("s_waitcnt lgkmcnt(0)" ::: "memory")
#define BAR()    __builtin_amdgcn_s_barrier()

__device__ __forceinline__ unsigned short f2bf(float f) {
  union { __bf16 h; unsigned short u; } cv;
  cv.h = (__bf16)f;
  return cv.u;
}
__device__ __forceinline__ bf16x8 cvt8(f32x4 a, f32x4 b) {
  bf16x8 r;
  r[0] = (__bf16)a[0]; r[1] = (__bf16)a[1]; r[2] = (__bf16)a[2]; r[3] = (__bf16)a[3];
  r[4] = (__bf16)b[0]; r[5] = (__bf16)b[1]; r[6] = (__bf16)b[2]; r[7] = (__bf16)b[3];
  return r;
}

// ---- fp32 S -> fragment-major bf16 layouts (wave-contiguous 1KB ring loads) ----
// Kf unit addr: (((b*16+t)*8 + w)*64 + kk)*1024 + lane*16
//    lane=(sh,sl): value S[b][t*256 + w*32 + sl][kk*16 + sh*8 + e], e=0..7
// Vf unit addr: (((b*16+t)*8 + w)*64 + ks*8+nf)*1024 + lane*16
//    lane=(lg,lr): value S[b][t*256 + ks*32 + lg*8 + e][w*128 + nf*16 + lr]
__global__ __launch_bounds__(256) void cvt_kernel(const float* __restrict__ S,
                                                  u8* __restrict__ Kf,
                                                  u8* __restrict__ Vf)
{
  __shared__ unsigned short tile[64][72];
  const int b  = blockIdx.z;
  const int dt = blockIdx.y;   // 0..15  (64 d each)
  const int st = blockIdx.x;   // 0..63  (64 s each)
  const int tid = threadIdx.x;
  const int t  = st >> 2;
  const float* Sbase = S + ((size_t)b*LS_ + (size_t)st*64)*DH_ + dt*64;

  // load 64x64 fp32 tile -> bf16 LDS
  #pragma unroll
  for (int k = 0; k < 4; ++k) {
    int fi  = tid + k*256;
    int row = fi >> 4;          // s within tile
    int c4  = fi & 15;          // float4 within 64 d
    float4 v = *reinterpret_cast<const float4*>(Sbase + (size_t)row*DH_ + c4*4);
    ushort4 h;
    h.x = f2bf(v.x); h.y = f2bf(v.y); h.z = f2bf(v.z); h.w = f2bf(v.w);
    *reinterpret_cast<ushort4*>(&tile[row][c4*4]) = h;
  }
  __syncthreads();

  // ---- Kf: 8x 1KB blocks (wloc 0..1, kkloc 0..3), fully coalesced writes ----
  #pragma unroll
  for (int h2 = 0; h2 < 2; ++h2) {
    int u    = tid + h2*256;        // 0..511
    int blk  = u >> 6;              // 0..7
    int wloc = blk >> 2;            // 0..1
    int kkl  = blk & 3;             // 0..3
    int lane = u & 63;
    int sh   = lane >> 5, sl = lane & 31;
    int srow = wloc*32 + sl;
    int scol = kkl*16 + sh*8;
    ushort4 h0 = *reinterpret_cast<const ushort4*>(&tile[srow][scol]);
    ushort4 h1 = *reinterpret_cast<const ushort4*>(&tile[srow][scol+4]);
    int w_g  = (st & 3)*2 + wloc;
    int kk_g = dt*4 + kkl;
    u8* dst = Kf + (size_t)(((b*16 + t)*8 + w_g)*64 + kk_g)*1024 + lane*16;
    *reinterpret_cast<ushort4*>(dst)     = h0;
    *reinterpret_cast<ushort4*>(dst + 8) = h1;
  }

  // ---- Vf: 8x 1KB blocks (ksloc 0..1, nfloc 0..3), transposed gather ----
  #pragma unroll
  for (int h2 = 0; h2 < 2; ++h2) {
    int u    = tid + h2*256;
    int blk  = u >> 6;
    int ksl  = blk >> 2;            // 0..1
    int nfl  = blk & 3;             // 0..3
    int lane = u & 63;
    int lg   = lane >> 4, lr = lane & 15;
    int srow = ksl*32 + lg*8;
    int dcol = nfl*16 + lr;
    ushort4 h0, h1;
    h0.x = tile[srow+0][dcol]; h0.y = tile[srow+1][dcol];
    h0.z = tile[srow+2][dcol]; h0.w = tile[srow+3][dcol];
    h1.x = tile[srow+4][dcol]; h1.y = tile[srow+5][dcol];
    h1.z = tile[srow+6][dcol]; h1.w = tile[srow+7][dcol];
    int w_g = dt >> 1;
    int i_g = ((st & 3)*2 + ksl)*8 + (dt & 1)*4 + nfl;
    u8* dst = Vf + (size_t)(((b*16 + t)*8 + w_g)*64 + i_g)*1024 + lane*16;
    *reinterpret_cast<ushort4*>(dst)     = h0;
    *reinterpret_cast<ushort4*>(dst + 8) = h1;
  }
}

// ---------------- fused flash attention, m==0 softmax ----------------
// QK^T: 32x32x16 MFMA, Q in lane-linear LDS; K ring (depth 8) from fragment-major ws.
// PV:   16x16x32 MFMA, P via LDS; V ring (depth 8) from fragment-major ws.
// Occupancy is LDS-capped at 1 block/CU (2 waves/SIMD) -> no register cap needed.
__global__ __launch_bounds__(NTH, 1) void attn_kernel(
    const float* __restrict__ Qg,
    const u8* __restrict__ Kf,
    const u8* __restrict__ Vf,
    float* __restrict__ Og)
{
  __shared__ __align__(16) unsigned char qlds[131072];  // [qf:2][kk:64][lane:64]*16B
  __shared__ __align__(16) unsigned char plds[32768];   // P [64 q][256 s] bf16 swizzled

  const int tid = threadIdx.x;
  const int w  = tid >> 6;
  const int l  = tid & 63;
  const int lg = l >> 4;
  const int lr = l & 15;
  const int sl = l & 31;
  const int sh = l >> 5;

  // XCD swizzle: batch -> XCD pair; same-XCD blocks share K/V streams in L2
  const int n    = blockIdx.x;
  const int xcd  = n & 7;
  const int slot = n >> 3;
  const int b    = xcd >> 1;
  const int qt   = (xcd & 1)*32 + slot;

  const float* Qbase = Qg + ((size_t)b*LQ_ + (size_t)qt*BQ_)*DH_;
  // per-thread ring base pointers (wave-contiguous 1KB units)
  const u8* kptr = Kf + (size_t)b*8388608 + (size_t)w*65536 + l*16;
  const u8* vptr = Vf + (size_t)b*8388608 + (size_t)w*65536 + l*16;

  bf16x8 bk[8];
  auto ld_bk = [&](int t, int kk) -> bf16x8 {
    return *reinterpret_cast<const bf16x8*>(kptr + (size_t)t*524288 + kk*1024);
  };
  bf16x8 bv[8];
  auto ld_bv = [&](int t, int i) -> bf16x8 {
    return *reinterpret_cast<const bf16x8*>(vptr + (size_t)t*524288 + i*1024);
  };

  // K-ring prologue for t=0 (depth 8, distance 7; in flight across Q-stage)
  #pragma unroll
  for (int i = 0; i < 7; ++i) bk[i] = ld_bk(0, i);

  // ---- stage Q fp32 -> bf16 into lane-linear fragment layout (once) ----
  #pragma unroll
  for (int it = 0; it < 16; ++it) {
    int u  = tid + it*NTH;          // 0..8191 fragment units of 16 B
    int qf = u >> 12;
    int kk = (u >> 6) & 63;
    int ll = u & 63;
    int q  = qf*32 + (ll & 31);
    int d  = kk*16 + (ll >> 5)*8;
    const float* p = Qbase + (size_t)q*DH_ + d;
    f32x4 v0 = *reinterpret_cast<const f32x4*>(p);
    f32x4 v1 = *reinterpret_cast<const f32x4*>(p + 4);
    *reinterpret_cast<bf16x8*>(qlds + (size_t)u*16) = cvt8(v0, v1);
  }

  f32x4 Oacc[4][8];
  #pragma unroll
  for (int i = 0; i < 4; ++i)
    #pragma unroll
    for (int j = 0; j < 8; ++j)
      Oacc[i][j] = (f32x4){0.f, 0.f, 0.f, 0.f};
  f32x4 lacc[4];
  #pragma unroll
  for (int i = 0; i < 4; ++i) lacc[i] = (f32x4){0.f, 0.f, 0.f, 0.f};

  bf16x8 ones;
  #pragma unroll
  for (int e = 0; e < 8; ++e) ones[e] = (__bf16)1.0f;

  WAITL();
  BAR();   // Q staged (global K-ring loads stay in flight)

  for (int t = 0; t < NT_; ++t) {
    // ================= QK^T: C[64 q][wave's 32 s], 32x32x16 =================
    f32x16 qk0, qk1;
    #pragma unroll
    for (int r = 0; r < 16; ++r) { qk0[r] = 0.f; qk1[r] = 0.f; }

    bf16x8 aqA0 = *reinterpret_cast<const bf16x8*>(qlds + l*16);
    bf16x8 aqA1 = *reinterpret_cast<const bf16x8*>(qlds + 65536 + l*16);

    #pragma unroll
    for (int kk = 0; kk < 64; ++kk) {
      if (kk < 57) bk[(kk + 7) & 7] = ld_bk(t, kk + 7);
      bf16x8 aqN0, aqN1;
      if (kk < 63) {
        aqN0 = *reinterpret_cast<const bf16x8*>(qlds + (kk + 1)*1024 + l*16);
        aqN1 = *reinterpret_cast<const bf16x8*>(qlds + 65536 + (kk + 1)*1024 + l*16);
      }
      __builtin_amdgcn_s_setprio(1);
      qk0 = __builtin_amdgcn_mfma_f32_32x32x16_bf16(aqA0, bk[kk & 7], qk0, 0, 0, 0);
      qk1 = __builtin_amdgcn_mfma_f32_32x32x16_bf16(aqA1, bk[kk & 7], qk1, 0, 0, 0);
      __builtin_amdgcn_s_setprio(0);
      if (kk < 63) { aqA0 = aqN0; aqA1 = aqN1; }
    }

    // ================= P = exp2(logit*scl) -> LDS =================
    const float SCL = 0.04508422f;   // (1/32) * log2(e)
    #pragma unroll
    for (int r = 0; r < 16; ++r) {
      int qrow = (r & 3) + 8*(r >> 2) + 4*sh;
      int s    = w*32 + sl;
      {
        float p = exp2f(qk0[r] * SCL);
        int q = qrow;
        *reinterpret_cast<__bf16*>(plds + q*512 + ((s*2) ^ ((q & 7) << 4))) = (__bf16)p;
      }
      {
        float p = exp2f(qk1[r] * SCL);
        int q = 32 + qrow;
        *reinterpret_cast<__bf16*>(plds + q*512 + ((s*2) ^ ((q & 7) << 4))) = (__bf16)p;
      }
    }

    // V-ring prologue (depth 8, distance 7; in flight across barrier)
    #pragma unroll
    for (int i = 0; i < 7; ++i) bv[i] = ld_bv(t, i);
    WAITL();
    BAR();   // #1: P visible to all waves

    // ================= PV: O[64 q][wave's 128 d] += P[64][256] @ V =================
    bf16x8 pa0, pa1, pa2, pa3, pn0, pn1, pn2, pn3;
    auto ldP = [&](int mq, int ks) -> bf16x8 {
      int q = mq*16 + lr;
      return *reinterpret_cast<const bf16x8*>(
          plds + q*512 + ((ks*64 + lg*16) ^ ((q & 7) << 4)));
    };
    pa0 = ldP(0, 0); pa1 = ldP(1, 0); pa2 = ldP(2, 0); pa3 = ldP(3, 0);

    #pragma unroll
    for (int ks = 0; ks < 8; ++ks) {
      #pragma unroll
      for (int nf = 0; nf < 8; ++nf) {
        const int i = ks*8 + nf;
        if (i < 57) bv[(i + 7) & 7] = ld_bv(t, i + 7);
        if (t + 1 < NT_ && i >= 57) bk[i - 57] = ld_bk(t + 1, i - 57);
        if (ks < 7) {
          if (nf == 1) pn0 = ldP(0, ks + 1);
          if (nf == 2) pn1 = ldP(1, ks + 1);
          if (nf == 3) pn2 = ldP(2, ks + 1);
          if (nf == 4) pn3 = ldP(3, ks + 1);
        }
        if (nf == 0 && w == 0) {
          lacc[0] = __builtin_amdgcn_mfma_f32_16x16x32_bf16(pa0, ones, lacc[0], 0, 0, 0);
          lacc[1] = __builtin_amdgcn_mfma_f32_16x16x32_bf16(pa1, ones, lacc[1], 0, 0, 0);
          lacc[2] = __builtin_amdgcn_mfma_f32_16x16x32_bf16(pa2, ones, lacc[2], 0, 0, 0);
          lacc[3] = __builtin_amdgcn_mfma_f32_16x16x32_bf16(pa3, ones, lacc[3], 0, 0, 0);
        }
        __builtin_amdgcn_s_setprio(1);
        Oacc[0][nf] = __builtin_amdgcn_mfma_f32_16x16x32_bf16(pa0, bv[i & 7], Oacc[0][nf], 0, 0, 0);
        Oacc[1][nf] = __builtin_amdgcn_mfma_f32_16x16x32_bf16(pa1, bv[i & 7], Oacc[1][nf], 0, 0, 0);
        Oacc[2][nf] = __builtin_amdgcn_mfma_f32_16x16x32_bf16(pa2, bv[i & 7], Oacc[2][nf], 0, 0, 0);
        Oacc[3][nf] = __builtin_amdgcn_mfma_f32_16x16x32_bf16(pa3, bv[i & 7], Oacc[3][nf], 0, 0, 0);
        __builtin_amdgcn_s_setprio(0);
      }
      if (ks < 7) { pa0 = pn0; pa1 = pn1; pa2 = pn2; pa3 = pn3; }
    }
    BAR();   // #2: P region free for next tile's writes
  }

  // ================= epilogue: l from wave-0 ones-MFMA, write O =================
  float* lred = (float*)plds;
  if (w == 0 && lr == 0) {
    #pragma unroll
    for (int mq = 0; mq < 4; ++mq)
      #pragma unroll
      for (int j = 0; j < 4; ++j)
        lred[mq*16 + lg*4 + j] = lacc[mq][j];
  }
  WAITL();
  BAR();

  float* Ob = Og + ((size_t)b*LQ_ + (size_t)qt*BQ_)*DH_;
  #pragma unroll
  for (int mq = 0; mq < 4; ++mq)
    #pragma unroll
    for (int j = 0; j < 4; ++j) {
      int q = mq*16 + lg*4 + j;
      float rinv = 1.0f / lred[q];
      #pragma unroll
      for (int nf = 0; nf < 8; ++nf)
        Ob[(size_t)q*DH_ + w*128 + nf*16 + lr] = Oacc[mq][nf][j] * rinv;
    }
}

// ---------------- correctness-only fallback (ws too small; never expected) ----------------
__global__ void attn_naive(const float* __restrict__ Q, const float* __restrict__ S,
                           float* __restrict__ O)
{
  const int row = blockIdx.x;
  const int b = row >> 12, q = row & 4095;
  const float* qp = Q + ((size_t)b*LQ_ + q)*DH_;
  const float* sp = S + (size_t)b*LS_*DH_;
  __shared__ float qs[DH_];
  __shared__ float osum[DH_];
  __shared__ float lsum;
  for (int i = threadIdx.x; i < DH_; i += 256) { qs[i] = qp[i]; osum[i] = 0.f; }
  if (threadIdx.x == 0) lsum = 0.f;
  __syncthreads();
  float lpart = 0.f;
  for (int s0 = threadIdx.x; s0 < LS_; s0 += 256) {
    const float* sr = sp + (size_t)s0*DH_;
    float dot = 0.f;
    for (int d = 0; d < DH_; ++d) dot += qs[d]*sr[d];
    float p = __expf(dot * 0.03125f);
    lpart += p;
    for (int d = 0; d < DH_; ++d) atomicAdd(&osum[d], p*sr[d]);
  }
  atomicAdd(&lsum, lpart);
  __syncthreads();
  float rinv = 1.0f / lsum;
  float* op = O + ((size_t)b*LQ_ + q)*DH_;
  for (int i = threadIdx.x; i < DH_; i += 256) op[i] = osum[i]*rinv;
}

extern "C" void kernel_launch(void* const* d_in, const int* in_sizes, int n_in,
                              void* d_out, int out_size, void* d_ws, size_t ws_size,
                              hipStream_t stream)
{
  const float* Q = (const float*)d_in[0];
  const float* S = (const float*)d_in[1];
  float* out = (float*)d_out;

  const size_t kf_bytes = (size_t)B_*NT_*8*64*1024;   // 32 MiB
  const size_t vf_bytes = (size_t)B_*NT_*8*64*1024;   // 32 MiB
  const size_t need = kf_bytes + vf_bytes;            // 64 MiB

  if (ws_size >= need) {
    u8* Kf = (u8*)d_ws;
    u8* Vf = Kf + kf_bytes;
    cvt_kernel<<<dim3(64, 16, 4), 256, 0, stream>>>(S, Kf, Vf);
    attn_kernel<<<dim3(256), NTH, 0, stream>>>(Q, Kf, Vf, out);
  } else {
    attn_naive<<<dim3(B_*LQ_), 256, 0, stream>>>(Q, S, out);
  }
}

// Round 8
// 347.656 us; speedup vs baseline: 1.3283x; 1.3283x over previous
//
#include <hip/hip_runtime.h>
#include <hip/hip_bf16.h>

#define B_   4
#define LQ_  4096
#define LS_  4096
#define DH_  1024
#define BQ_  64
#define BS_  256
#define NT_  (LS_/BS_)   /* 16 */
#define NTH  512

typedef __bf16 bf16x8 __attribute__((ext_vector_type(8)));
typedef float  f32x4  __attribute__((ext_vector_type(4)));
typedef float  f32x16 __attribute__((ext_vector_type(16)));
typedef unsigned char u8;

#define WAITL()  asm volatile("s_waitcnt lgkmcnt(0)" ::: "memory")
#define BAR()    __builtin_amdgcn_s_barrier()

__device__ __forceinline__ unsigned short f2bf(float f) {
  union { __bf16 h; unsigned short u; } cv;
  cv.h = (__bf16)f;
  return cv.u;
}
__device__ __forceinline__ bf16x8 cvt8(f32x4 a, f32x4 b) {
  bf16x8 r;
  r[0] = (__bf16)a[0]; r[1] = (__bf16)a[1]; r[2] = (__bf16)a[2]; r[3] = (__bf16)a[3];
  r[4] = (__bf16)b[0]; r[5] = (__bf16)b[1]; r[6] = (__bf16)b[2]; r[7] = (__bf16)b[3];
  return r;
}

// ---- fp32 S -> fragment-major bf16 layouts (wave-contiguous 1KB ring loads) ----
__global__ __launch_bounds__(256) void cvt_kernel(const float* __restrict__ S,
                                                  u8* __restrict__ Kf,
                                                  u8* __restrict__ Vf)
{
  __shared__ unsigned short tile[64][72];
  const int b  = blockIdx.z;
  const int dt = blockIdx.y;   // 0..15  (64 d each)
  const int st = blockIdx.x;   // 0..63  (64 s each)
  const int tid = threadIdx.x;
  const int t  = st >> 2;
  const float* Sbase = S + ((size_t)b*LS_ + (size_t)st*64)*DH_ + dt*64;

  #pragma unroll
  for (int k = 0; k < 4; ++k) {
    int fi  = tid + k*256;
    int row = fi >> 4;
    int c4  = fi & 15;
    float4 v = *reinterpret_cast<const float4*>(Sbase + (size_t)row*DH_ + c4*4);
    ushort4 h;
    h.x = f2bf(v.x); h.y = f2bf(v.y); h.z = f2bf(v.z); h.w = f2bf(v.w);
    *reinterpret_cast<ushort4*>(&tile[row][c4*4]) = h;
  }
  __syncthreads();

  // Kf: 8x 1KB blocks
  #pragma unroll
  for (int h2 = 0; h2 < 2; ++h2) {
    int u    = tid + h2*256;
    int blk  = u >> 6;
    int wloc = blk >> 2;
    int kkl  = blk & 3;
    int lane = u & 63;
    int sh   = lane >> 5, sl = lane & 31;
    int srow = wloc*32 + sl;
    int scol = kkl*16 + sh*8;
    ushort4 h0 = *reinterpret_cast<const ushort4*>(&tile[srow][scol]);
    ushort4 h1 = *reinterpret_cast<const ushort4*>(&tile[srow][scol+4]);
    int w_g  = (st & 3)*2 + wloc;
    int kk_g = dt*4 + kkl;
    u8* dst = Kf + (size_t)(((b*16 + t)*8 + w_g)*64 + kk_g)*1024 + lane*16;
    *reinterpret_cast<ushort4*>(dst)     = h0;
    *reinterpret_cast<ushort4*>(dst + 8) = h1;
  }

  // Vf: 8x 1KB blocks (transposed gather)
  #pragma unroll
  for (int h2 = 0; h2 < 2; ++h2) {
    int u    = tid + h2*256;
    int blk  = u >> 6;
    int ksl  = blk >> 2;
    int nfl  = blk & 3;
    int lane = u & 63;
    int lg   = lane >> 4, lr = lane & 15;
    int srow = ksl*32 + lg*8;
    int dcol = nfl*16 + lr;
    ushort4 h0, h1;
    h0.x = tile[srow+0][dcol]; h0.y = tile[srow+1][dcol];
    h0.z = tile[srow+2][dcol]; h0.w = tile[srow+3][dcol];
    h1.x = tile[srow+4][dcol]; h1.y = tile[srow+5][dcol];
    h1.z = tile[srow+6][dcol]; h1.w = tile[srow+7][dcol];
    int w_g = dt >> 1;
    int i_g = ((st & 3)*2 + ksl)*8 + (dt & 1)*4 + nfl;
    u8* dst = Vf + (size_t)(((b*16 + t)*8 + w_g)*64 + i_g)*1024 + lane*16;
    *reinterpret_cast<ushort4*>(dst)     = h0;
    *reinterpret_cast<ushort4*>(dst + 8) = h1;
  }
}

// ---------------- fused flash attention, m==0 softmax, cross-tile pipelined ----------------
// Per tile-period one fused 64-iter loop runs QK^T(t) [LDS+MFMA heavy] and
// PV(t-1) [L2+MFMA heavy] in a single instruction stream so all three
// resources (MFMA pipe, LDS port, L2 port) overlap. 2 barriers per tile
// around the softmax/P-write region only.
__global__ __launch_bounds__(NTH, 1) void attn_kernel(
    const float* __restrict__ Qg,
    const u8* __restrict__ Kf,
    const u8* __restrict__ Vf,
    float* __restrict__ Og)
{
  __shared__ __align__(16) unsigned char qlds[131072];  // [qf:2][kk:64][lane:64]*16B
  __shared__ __align__(16) unsigned char plds[32768];   // P [64 q][256 s] bf16 swizzled

  const int tid = threadIdx.x;
  const int w  = tid >> 6;
  const int l  = tid & 63;
  const int lg = l >> 4;
  const int lr = l & 15;
  const int sl = l & 31;
  const int sh = l >> 5;

  const int n    = blockIdx.x;
  const int xcd  = n & 7;
  const int slot = n >> 3;
  const int b    = xcd >> 1;
  const int qt   = (xcd & 1)*32 + slot;

  const float* Qbase = Qg + ((size_t)b*LQ_ + (size_t)qt*BQ_)*DH_;
  const u8* kptr = Kf + (size_t)b*8388608 + (size_t)w*65536 + l*16;
  const u8* vptr = Vf + (size_t)b*8388608 + (size_t)w*65536 + l*16;

  bf16x8 bk[4];
  auto ld_bk = [&](int t, int kk) -> bf16x8 {
    return *reinterpret_cast<const bf16x8*>(kptr + (size_t)t*524288 + kk*1024);
  };
  bf16x8 bv[4];
  auto ld_bv = [&](int t, int i) -> bf16x8 {
    return *reinterpret_cast<const bf16x8*>(vptr + (size_t)t*524288 + i*1024);
  };
  auto ldP = [&](int mq, int ks) -> bf16x8 {
    int q = mq*16 + lr;
    return *reinterpret_cast<const bf16x8*>(
        plds + q*512 + ((ks*64 + lg*16) ^ ((q & 7) << 4)));
  };

  // K-ring prologue for t=0 (in flight across Q staging)
  bk[0] = ld_bk(0, 0); bk[1] = ld_bk(0, 1); bk[2] = ld_bk(0, 2);

  // ---- stage Q fp32 -> bf16 into lane-linear fragment layout (once) ----
  #pragma unroll
  for (int it = 0; it < 16; ++it) {
    int u  = tid + it*NTH;
    int qf = u >> 12;
    int kk = (u >> 6) & 63;
    int ll = u & 63;
    int q  = qf*32 + (ll & 31);
    int d  = kk*16 + (ll >> 5)*8;
    const float* p = Qbase + (size_t)q*DH_ + d;
    f32x4 v0 = *reinterpret_cast<const f32x4*>(p);
    f32x4 v1 = *reinterpret_cast<const f32x4*>(p + 4);
    *reinterpret_cast<bf16x8*>(qlds + (size_t)u*16) = cvt8(v0, v1);
  }

  f32x4 Oacc[4][8];
  #pragma unroll
  for (int i = 0; i < 4; ++i)
    #pragma unroll
    for (int j = 0; j < 8; ++j)
      Oacc[i][j] = (f32x4){0.f, 0.f, 0.f, 0.f};
  f32x4 lacc[4];
  #pragma unroll
  for (int i = 0; i < 4; ++i) lacc[i] = (f32x4){0.f, 0.f, 0.f, 0.f};

  bf16x8 ones;
  #pragma unroll
  for (int e = 0; e < 8; ++e) ones[e] = (__bf16)1.0f;

  f32x16 qk0, qk1;
  const float SCL = 0.04508422f;   // (1/32) * log2(e)

  WAITL();
  BAR();   // Q staged

  // ================= QK-only prologue: tile 0 =================
  #pragma unroll
  for (int r = 0; r < 16; ++r) { qk0[r] = 0.f; qk1[r] = 0.f; }
  {
    bf16x8 aqA0 = *reinterpret_cast<const bf16x8*>(qlds + l*16);
    bf16x8 aqA1 = *reinterpret_cast<const bf16x8*>(qlds + 65536 + l*16);
    #pragma unroll
    for (int kk = 0; kk < 64; ++kk) {
      if (kk < 61) bk[(kk + 3) & 3] = ld_bk(0, kk + 3);
      bf16x8 aqN0, aqN1;
      if (kk < 63) {
        aqN0 = *reinterpret_cast<const bf16x8*>(qlds + (kk + 1)*1024 + l*16);
        aqN1 = *reinterpret_cast<const bf16x8*>(qlds + 65536 + (kk + 1)*1024 + l*16);
      }
      qk0 = __builtin_amdgcn_mfma_f32_32x32x16_bf16(aqA0, bk[kk & 3], qk0, 0, 0, 0);
      qk1 = __builtin_amdgcn_mfma_f32_32x32x16_bf16(aqA1, bk[kk & 3], qk1, 0, 0, 0);
      if (kk < 63) { aqA0 = aqN0; aqA1 = aqN1; }
    }
  }

  // ================= main: for t = 1..15, fused QK(t) + PV(t-1) =================
  for (int t = 1; t < NT_; ++t) {
    BAR();   // all waves' plds reads of P(t-2) done

    // softmax(t-1): P = exp2(scl*logit) -> plds
    #pragma unroll
    for (int r = 0; r < 16; ++r) {
      int qrow = (r & 3) + 8*(r >> 2) + 4*sh;
      int s    = w*32 + sl;
      {
        float p = exp2f(qk0[r] * SCL);
        int q = qrow;
        *reinterpret_cast<__bf16*>(plds + q*512 + ((s*2) ^ ((q & 7) << 4))) = (__bf16)p;
      }
      {
        float p = exp2f(qk1[r] * SCL);
        int q = 32 + qrow;
        *reinterpret_cast<__bf16*>(plds + q*512 + ((s*2) ^ ((q & 7) << 4))) = (__bf16)p;
      }
    }

    // ring prologues for the fused loop (latency hidden under softmax + barrier)
    bk[0] = ld_bk(t, 0); bk[1] = ld_bk(t, 1); bk[2] = ld_bk(t, 2);
    bv[0] = ld_bv(t-1, 0); bv[1] = ld_bv(t-1, 1); bv[2] = ld_bv(t-1, 2);

    WAITL();
    BAR();   // P(t-1) visible

    #pragma unroll
    for (int r = 0; r < 16; ++r) { qk0[r] = 0.f; qk1[r] = 0.f; }

    bf16x8 aqA0 = *reinterpret_cast<const bf16x8*>(qlds + l*16);
    bf16x8 aqA1 = *reinterpret_cast<const bf16x8*>(qlds + 65536 + l*16);
    bf16x8 pa0, pa1, pa2, pa3;

    #pragma unroll
    for (int i = 0; i < 64; ++i) {
      const int ks = i >> 3, nf = i & 7;
      // ---- QK(t) part ----
      if (i < 61) bk[(i + 3) & 3] = ld_bk(t, i + 3);
      bf16x8 aqN0, aqN1;
      if (i < 63) {
        aqN0 = *reinterpret_cast<const bf16x8*>(qlds + (i + 1)*1024 + l*16);
        aqN1 = *reinterpret_cast<const bf16x8*>(qlds + 65536 + (i + 1)*1024 + l*16);
      }
      qk0 = __builtin_amdgcn_mfma_f32_32x32x16_bf16(aqA0, bk[i & 3], qk0, 0, 0, 0);
      qk1 = __builtin_amdgcn_mfma_f32_32x32x16_bf16(aqA1, bk[i & 3], qk1, 0, 0, 0);
      if (i < 63) { aqA0 = aqN0; aqA1 = aqN1; }

      // ---- PV(t-1) part ----
      if (i < 61) bv[(i + 3) & 3] = ld_bv(t-1, i + 3);
      if (nf == 0) {
        pa0 = ldP(0, ks); pa1 = ldP(1, ks); pa2 = ldP(2, ks); pa3 = ldP(3, ks);
        if (w == 0) {
          lacc[0] = __builtin_amdgcn_mfma_f32_16x16x32_bf16(pa0, ones, lacc[0], 0, 0, 0);
          lacc[1] = __builtin_amdgcn_mfma_f32_16x16x32_bf16(pa1, ones, lacc[1], 0, 0, 0);
          lacc[2] = __builtin_amdgcn_mfma_f32_16x16x32_bf16(pa2, ones, lacc[2], 0, 0, 0);
          lacc[3] = __builtin_amdgcn_mfma_f32_16x16x32_bf16(pa3, ones, lacc[3], 0, 0, 0);
        }
      }
      Oacc[0][nf] = __builtin_amdgcn_mfma_f32_16x16x32_bf16(pa0, bv[i & 3], Oacc[0][nf], 0, 0, 0);
      Oacc[1][nf] = __builtin_amdgcn_mfma_f32_16x16x32_bf16(pa1, bv[i & 3], Oacc[1][nf], 0, 0, 0);
      Oacc[2][nf] = __builtin_amdgcn_mfma_f32_16x16x32_bf16(pa2, bv[i & 3], Oacc[2][nf], 0, 0, 0);
      Oacc[3][nf] = __builtin_amdgcn_mfma_f32_16x16x32_bf16(pa3, bv[i & 3], Oacc[3][nf], 0, 0, 0);
    }
  }

  // ================= epilogue: softmax(15) + PV-only =================
  BAR();
  #pragma unroll
  for (int r = 0; r < 16; ++r) {
    int qrow = (r & 3) + 8*(r >> 2) + 4*sh;
    int s    = w*32 + sl;
    {
      float p = exp2f(qk0[r] * SCL);
      int q = qrow;
      *reinterpret_cast<__bf16*>(plds + q*512 + ((s*2) ^ ((q & 7) << 4))) = (__bf16)p;
    }
    {
      float p = exp2f(qk1[r] * SCL);
      int q = 32 + qrow;
      *reinterpret_cast<__bf16*>(plds + q*512 + ((s*2) ^ ((q & 7) << 4))) = (__bf16)p;
    }
  }
  bv[0] = ld_bv(NT_-1, 0); bv[1] = ld_bv(NT_-1, 1); bv[2] = ld_bv(NT_-1, 2);
  WAITL();
  BAR();

  {
    bf16x8 pa0, pa1, pa2, pa3;
    #pragma unroll
    for (int i = 0; i < 64; ++i) {
      const int ks = i >> 3, nf = i & 7;
      if (i < 61) bv[(i + 3) & 3] = ld_bv(NT_-1, i + 3);
      if (nf == 0) {
        pa0 = ldP(0, ks); pa1 = ldP(1, ks); pa2 = ldP(2, ks); pa3 = ldP(3, ks);
        if (w == 0) {
          lacc[0] = __builtin_amdgcn_mfma_f32_16x16x32_bf16(pa0, ones, lacc[0], 0, 0, 0);
          lacc[1] = __builtin_amdgcn_mfma_f32_16x16x32_bf16(pa1, ones, lacc[1], 0, 0, 0);
          lacc[2] = __builtin_amdgcn_mfma_f32_16x16x32_bf16(pa2, ones, lacc[2], 0, 0, 0);
          lacc[3] = __builtin_amdgcn_mfma_f32_16x16x32_bf16(pa3, ones, lacc[3], 0, 0, 0);
        }
      }
      Oacc[0][nf] = __builtin_amdgcn_mfma_f32_16x16x32_bf16(pa0, bv[i & 3], Oacc[0][nf], 0, 0, 0);
      Oacc[1][nf] = __builtin_amdgcn_mfma_f32_16x16x32_bf16(pa1, bv[i & 3], Oacc[1][nf], 0, 0, 0);
      Oacc[2][nf] = __builtin_amdgcn_mfma_f32_16x16x32_bf16(pa2, bv[i & 3], Oacc[2][nf], 0, 0, 0);
      Oacc[3][nf] = __builtin_amdgcn_mfma_f32_16x16x32_bf16(pa3, bv[i & 3], Oacc[3][nf], 0, 0, 0);
    }
  }
  BAR();

  // ================= l from wave-0 ones-MFMA, write O =================
  float* lred = (float*)plds;
  if (w == 0 && lr == 0) {
    #pragma unroll
    for (int mq = 0; mq < 4; ++mq)
      #pragma unroll
      for (int j = 0; j < 4; ++j)
        lred[mq*16 + lg*4 + j] = lacc[mq][j];
  }
  WAITL();
  BAR();

  float* Ob = Og + ((size_t)b*LQ_ + (size_t)qt*BQ_)*DH_;
  #pragma unroll
  for (int mq = 0; mq < 4; ++mq)
    #pragma unroll
    for (int j = 0; j < 4; ++j) {
      int q = mq*16 + lg*4 + j;
      float rinv = 1.0f / lred[q];
      #pragma unroll
      for (int nf = 0; nf < 8; ++nf)
        Ob[(size_t)q*DH_ + w*128 + nf*16 + lr] = Oacc[mq][nf][j] * rinv;
    }
}

// ---------------- correctness-only fallback (ws too small; never expected) ----------------
__global__ void attn_naive(const float* __restrict__ Q, const float* __restrict__ S,
                           float* __restrict__ O)
{
  const int row = blockIdx.x;
  const int b = row >> 12, q = row & 4095;
  const float* qp = Q + ((size_t)b*LQ_ + q)*DH_;
  const float* sp = S + (size_t)b*LS_*DH_;
  __shared__ float qs[DH_];
  __shared__ float osum[DH_];
  __shared__ float lsum;
  for (int i = threadIdx.x; i < DH_; i += 256) { qs[i] = qp[i]; osum[i] = 0.f; }
  if (threadIdx.x == 0) lsum = 0.f;
  __syncthreads();
  float lpart = 0.f;
  for (int s0 = threadIdx.x; s0 < LS_; s0 += 256) {
    const float* sr = sp + (size_t)s0*DH_;
    float dot = 0.f;
    for (int d = 0; d < DH_; ++d) dot += qs[d]*sr[d];
    float p = __expf(dot * 0.03125f);
    lpart += p;
    for (int d = 0; d < DH_; ++d) atomicAdd(&osum[d], p*sr[d]);
  }
  atomicAdd(&lsum, lpart);
  __syncthreads();
  float rinv = 1.0f / lsum;
  float* op = O + ((size_t)b*LQ_ + q)*DH_;
  for (int i = threadIdx.x; i < DH_; i += 256) op[i] = osum[i]*rinv;
}

extern "C" void kernel_launch(void* const* d_in, const int* in_sizes, int n_in,
                              void* d_out, int out_size, void* d_ws, size_t ws_size,
                              hipStream_t stream)
{
  const float* Q = (const float*)d_in[0];
  const float* S = (const float*)d_in[1];
  float* out = (float*)d_out;

  const size_t kf_bytes = (size_t)B_*NT_*8*64*1024;   // 32 MiB
  const size_t vf_bytes = (size_t)B_*NT_*8*64*1024;   // 32 MiB
  const size_t need = kf_bytes + vf_bytes;            // 64 MiB

  if (ws_size >= need) {
    u8* Kf = (u8*)d_ws;
    u8* Vf = Kf + kf_bytes;
    cvt_kernel<<<dim3(64, 16, 4), 256, 0, stream>>>(S, Kf, Vf);
    attn_kernel<<<dim3(256), NTH, 0, stream>>>(Q, Kf, Vf, out);
  } else {
    attn_naive<<<dim3(B_*LQ_), 256, 0, stream>>>(Q, S, out);
  }
}

// Round 9
// 297.021 us; speedup vs baseline: 1.5548x; 1.1705x over previous
//
#include <hip/hip_runtime.h>
#include <hip/hip_bf16.h>

#define B_   4
#define LQ_  4096
#define LS_  4096
#define DH_  1024
#define BQ_  64
#define BS_  256
#define NT_  (LS_/BS_)   /* 16 */
#define NTH  512

typedef __bf16 bf16x8 __attribute__((ext_vector_type(8)));
typedef float  f32x4  __attribute__((ext_vector_type(4)));
typedef float  f32x16 __attribute__((ext_vector_type(16)));
typedef unsigned char u8;

#define WAITL()  asm volatile("s_waitcnt lgkmcnt(0)" ::: "memory")
#define BAR()    __builtin_amdgcn_s_barrier()

__device__ __forceinline__ unsigned short f2bf(float f) {
  union { __bf16 h; unsigned short u; } cv;
  cv.h = (__bf16)f;
  return cv.u;
}
__device__ __forceinline__ bf16x8 cvt8(f32x4 a, f32x4 b) {
  bf16x8 r;
  r[0] = (__bf16)a[0]; r[1] = (__bf16)a[1]; r[2] = (__bf16)a[2]; r[3] = (__bf16)a[3];
  r[4] = (__bf16)b[0]; r[5] = (__bf16)b[1]; r[6] = (__bf16)b[2]; r[7] = (__bf16)b[3];
  return r;
}

// ---- fp32 S -> fragment-major bf16 layouts (wave-contiguous 1KB ring loads) ----
__global__ __launch_bounds__(256) void cvt_kernel(const float* __restrict__ S,
                                                  u8* __restrict__ Kf,
                                                  u8* __restrict__ Vf)
{
  __shared__ unsigned short tile[64][72];
  const int b  = blockIdx.z;
  const int dt = blockIdx.y;   // 0..15  (64 d each)
  const int st = blockIdx.x;   // 0..63  (64 s each)
  const int tid = threadIdx.x;
  const int t  = st >> 2;
  const float* Sbase = S + ((size_t)b*LS_ + (size_t)st*64)*DH_ + dt*64;

  #pragma unroll
  for (int k = 0; k < 4; ++k) {
    int fi  = tid + k*256;
    int row = fi >> 4;
    int c4  = fi & 15;
    float4 v = *reinterpret_cast<const float4*>(Sbase + (size_t)row*DH_ + c4*4);
    ushort4 h;
    h.x = f2bf(v.x); h.y = f2bf(v.y); h.z = f2bf(v.z); h.w = f2bf(v.w);
    *reinterpret_cast<ushort4*>(&tile[row][c4*4]) = h;
  }
  __syncthreads();

  // Kf: 8x 1KB blocks
  #pragma unroll
  for (int h2 = 0; h2 < 2; ++h2) {
    int u    = tid + h2*256;
    int blk  = u >> 6;
    int wloc = blk >> 2;
    int kkl  = blk & 3;
    int lane = u & 63;
    int sh   = lane >> 5, sl = lane & 31;
    int srow = wloc*32 + sl;
    int scol = kkl*16 + sh*8;
    ushort4 h0 = *reinterpret_cast<const ushort4*>(&tile[srow][scol]);
    ushort4 h1 = *reinterpret_cast<const ushort4*>(&tile[srow][scol+4]);
    int w_g  = (st & 3)*2 + wloc;
    int kk_g = dt*4 + kkl;
    u8* dst = Kf + (size_t)(((b*16 + t)*8 + w_g)*64 + kk_g)*1024 + lane*16;
    *reinterpret_cast<ushort4*>(dst)     = h0;
    *reinterpret_cast<ushort4*>(dst + 8) = h1;
  }

  // Vf: 8x 1KB blocks (transposed gather)
  #pragma unroll
  for (int h2 = 0; h2 < 2; ++h2) {
    int u    = tid + h2*256;
    int blk  = u >> 6;
    int ksl  = blk >> 2;
    int nfl  = blk & 3;
    int lane = u & 63;
    int lg   = lane >> 4, lr = lane & 15;
    int srow = ksl*32 + lg*8;
    int dcol = nfl*16 + lr;
    ushort4 h0, h1;
    h0.x = tile[srow+0][dcol]; h0.y = tile[srow+1][dcol];
    h0.z = tile[srow+2][dcol]; h0.w = tile[srow+3][dcol];
    h1.x = tile[srow+4][dcol]; h1.y = tile[srow+5][dcol];
    h1.z = tile[srow+6][dcol]; h1.w = tile[srow+7][dcol];
    int w_g = dt >> 1;
    int i_g = ((st & 3)*2 + ksl)*8 + (dt & 1)*4 + nfl;
    u8* dst = Vf + (size_t)(((b*16 + t)*8 + w_g)*64 + i_g)*1024 + lane*16;
    *reinterpret_cast<ushort4*>(dst)     = h0;
    *reinterpret_cast<ushort4*>(dst + 8) = h1;
  }
}

// ---------------- fused flash attention, m==0 softmax, cross-tile pipelined ----------------
// Fused QK^T(t) + PV(t-1) in one instruction stream; partial unroll (8-wide
// bodies, outer loops rolled) keeps hot code ~7 KB -> I$-resident.
__global__ __launch_bounds__(NTH, 1) void attn_kernel(
    const float* __restrict__ Qg,
    const u8* __restrict__ Kf,
    const u8* __restrict__ Vf,
    float* __restrict__ Og)
{
  __shared__ __align__(16) unsigned char qlds[131072];  // [qf:2][kk:64][lane:64]*16B
  __shared__ __align__(16) unsigned char plds[32768];   // P [64 q][256 s] bf16 swizzled

  const int tid = threadIdx.x;
  const int w  = tid >> 6;
  const int l  = tid & 63;
  const int lg = l >> 4;
  const int lr = l & 15;
  const int sl = l & 31;
  const int sh = l >> 5;

  const int n    = blockIdx.x;
  const int xcd  = n & 7;
  const int slot = n >> 3;
  const int b    = xcd >> 1;
  const int qt   = (xcd & 1)*32 + slot;

  const float* Qbase = Qg + ((size_t)b*LQ_ + (size_t)qt*BQ_)*DH_;
  const u8* kptr = Kf + (size_t)b*8388608 + (size_t)w*65536 + l*16;
  const u8* vptr = Vf + (size_t)b*8388608 + (size_t)w*65536 + l*16;

  bf16x8 bk[4];
  auto ld_bk = [&](int t, int kk) -> bf16x8 {
    return *reinterpret_cast<const bf16x8*>(kptr + (size_t)t*524288 + kk*1024);
  };
  bf16x8 bv[4];
  auto ld_bv = [&](int t, int i) -> bf16x8 {
    return *reinterpret_cast<const bf16x8*>(vptr + (size_t)t*524288 + i*1024);
  };
  auto ldP = [&](int mq, int ks) -> bf16x8 {
    int q = mq*16 + lr;
    return *reinterpret_cast<const bf16x8*>(
        plds + q*512 + ((ks*64 + lg*16) ^ ((q & 7) << 4)));
  };

  // K-ring prologue for t=0 (in flight across Q staging)
  bk[0] = ld_bk(0, 0); bk[1] = ld_bk(0, 1); bk[2] = ld_bk(0, 2);

  // ---- stage Q fp32 -> bf16 into lane-linear fragment layout (once) ----
  #pragma unroll
  for (int it = 0; it < 16; ++it) {
    int u  = tid + it*NTH;
    int qf = u >> 12;
    int kk = (u >> 6) & 63;
    int ll = u & 63;
    int q  = qf*32 + (ll & 31);
    int d  = kk*16 + (ll >> 5)*8;
    const float* p = Qbase + (size_t)q*DH_ + d;
    f32x4 v0 = *reinterpret_cast<const f32x4*>(p);
    f32x4 v1 = *reinterpret_cast<const f32x4*>(p + 4);
    *reinterpret_cast<bf16x8*>(qlds + (size_t)u*16) = cvt8(v0, v1);
  }

  f32x4 Oacc[4][8];
  #pragma unroll
  for (int i = 0; i < 4; ++i)
    #pragma unroll
    for (int j = 0; j < 8; ++j)
      Oacc[i][j] = (f32x4){0.f, 0.f, 0.f, 0.f};
  f32x4 lacc[4];
  #pragma unroll
  for (int i = 0; i < 4; ++i) lacc[i] = (f32x4){0.f, 0.f, 0.f, 0.f};

  bf16x8 ones;
  #pragma unroll
  for (int e = 0; e < 8; ++e) ones[e] = (__bf16)1.0f;

  f32x16 qk0, qk1;
  const float SCL = 0.04508422f;   // (1/32) * log2(e)

  WAITL();
  BAR();   // Q staged

  // ================= QK-only prologue: tile 0 =================
  #pragma unroll
  for (int r = 0; r < 16; ++r) { qk0[r] = 0.f; qk1[r] = 0.f; }
  {
    bf16x8 aqA0 = *reinterpret_cast<const bf16x8*>(qlds + l*16);
    bf16x8 aqA1 = *reinterpret_cast<const bf16x8*>(qlds + 65536 + l*16);
    #pragma unroll 1
    for (int ib = 0; ib < 7; ++ib) {
      #pragma unroll
      for (int j = 0; j < 8; ++j) {
        const int kk = ib*8 + j;                      // 0..55
        bk[(j + 3) & 3] = ld_bk(0, kk + 3);
        bf16x8 aqN0 = *reinterpret_cast<const bf16x8*>(qlds + (kk + 1)*1024 + l*16);
        bf16x8 aqN1 = *reinterpret_cast<const bf16x8*>(qlds + 65536 + (kk + 1)*1024 + l*16);
        qk0 = __builtin_amdgcn_mfma_f32_32x32x16_bf16(aqA0, bk[j & 3], qk0, 0, 0, 0);
        qk1 = __builtin_amdgcn_mfma_f32_32x32x16_bf16(aqA1, bk[j & 3], qk1, 0, 0, 0);
        aqA0 = aqN0; aqA1 = aqN1;
      }
    }
    #pragma unroll
    for (int j = 56; j < 64; ++j) {                   // static tail
      if (j < 61) bk[(j + 3) & 3] = ld_bk(0, j + 3);
      bf16x8 aqN0, aqN1;
      if (j < 63) {
        aqN0 = *reinterpret_cast<const bf16x8*>(qlds + (j + 1)*1024 + l*16);
        aqN1 = *reinterpret_cast<const bf16x8*>(qlds + 65536 + (j + 1)*1024 + l*16);
      }
      qk0 = __builtin_amdgcn_mfma_f32_32x32x16_bf16(aqA0, bk[j & 3], qk0, 0, 0, 0);
      qk1 = __builtin_amdgcn_mfma_f32_32x32x16_bf16(aqA1, bk[j & 3], qk1, 0, 0, 0);
      if (j < 63) { aqA0 = aqN0; aqA1 = aqN1; }
    }
  }

  // ================= main: for t = 1..15, fused QK(t) + PV(t-1) =================
  #pragma unroll 1
  for (int t = 1; t < NT_; ++t) {
    BAR();   // all waves' plds reads of P(t-2) done

    // softmax(t-1): P = exp2(scl*logit) -> plds
    #pragma unroll
    for (int r = 0; r < 16; ++r) {
      int qrow = (r & 3) + 8*(r >> 2) + 4*sh;
      int s    = w*32 + sl;
      {
        float p = exp2f(qk0[r] * SCL);
        int q = qrow;
        *reinterpret_cast<__bf16*>(plds + q*512 + ((s*2) ^ ((q & 7) << 4))) = (__bf16)p;
      }
      {
        float p = exp2f(qk1[r] * SCL);
        int q = 32 + qrow;
        *reinterpret_cast<__bf16*>(plds + q*512 + ((s*2) ^ ((q & 7) << 4))) = (__bf16)p;
      }
    }

    // ring prologues (latency hidden under softmax + barrier)
    bk[0] = ld_bk(t, 0); bk[1] = ld_bk(t, 1); bk[2] = ld_bk(t, 2);
    bv[0] = ld_bv(t-1, 0); bv[1] = ld_bv(t-1, 1); bv[2] = ld_bv(t-1, 2);

    WAITL();
    BAR();   // P(t-1) visible

    #pragma unroll
    for (int r = 0; r < 16; ++r) { qk0[r] = 0.f; qk1[r] = 0.f; }

    bf16x8 aqA0 = *reinterpret_cast<const bf16x8*>(qlds + l*16);
    bf16x8 aqA1 = *reinterpret_cast<const bf16x8*>(qlds + 65536 + l*16);
    bf16x8 pa0, pa1, pa2, pa3;

    #pragma unroll 1
    for (int ib = 0; ib < 7; ++ib) {
      #pragma unroll
      for (int j = 0; j < 8; ++j) {
        const int i = ib*8 + j;                       // 0..55
        // ---- QK(t) ----
        bk[(j + 3) & 3] = ld_bk(t, i + 3);
        bf16x8 aqN0 = *reinterpret_cast<const bf16x8*>(qlds + (i + 1)*1024 + l*16);
        bf16x8 aqN1 = *reinterpret_cast<const bf16x8*>(qlds + 65536 + (i + 1)*1024 + l*16);
        qk0 = __builtin_amdgcn_mfma_f32_32x32x16_bf16(aqA0, bk[j & 3], qk0, 0, 0, 0);
        qk1 = __builtin_amdgcn_mfma_f32_32x32x16_bf16(aqA1, bk[j & 3], qk1, 0, 0, 0);
        aqA0 = aqN0; aqA1 = aqN1;
        // ---- PV(t-1) ----
        bv[(j + 3) & 3] = ld_bv(t-1, i + 3);
        if (j == 0) {
          pa0 = ldP(0, ib); pa1 = ldP(1, ib); pa2 = ldP(2, ib); pa3 = ldP(3, ib);
          if (w == 0) {
            lacc[0] = __builtin_amdgcn_mfma_f32_16x16x32_bf16(pa0, ones, lacc[0], 0, 0, 0);
            lacc[1] = __builtin_amdgcn_mfma_f32_16x16x32_bf16(pa1, ones, lacc[1], 0, 0, 0);
            lacc[2] = __builtin_amdgcn_mfma_f32_16x16x32_bf16(pa2, ones, lacc[2], 0, 0, 0);
            lacc[3] = __builtin_amdgcn_mfma_f32_16x16x32_bf16(pa3, ones, lacc[3], 0, 0, 0);
          }
        }
        Oacc[0][j] = __builtin_amdgcn_mfma_f32_16x16x32_bf16(pa0, bv[j & 3], Oacc[0][j], 0, 0, 0);
        Oacc[1][j] = __builtin_amdgcn_mfma_f32_16x16x32_bf16(pa1, bv[j & 3], Oacc[1][j], 0, 0, 0);
        Oacc[2][j] = __builtin_amdgcn_mfma_f32_16x16x32_bf16(pa2, bv[j & 3], Oacc[2][j], 0, 0, 0);
        Oacc[3][j] = __builtin_amdgcn_mfma_f32_16x16x32_bf16(pa3, bv[j & 3], Oacc[3][j], 0, 0, 0);
      }
    }
    #pragma unroll
    for (int j = 56; j < 64; ++j) {                   // static tail, i = j
      const int nf = j & 7;
      if (j < 61) bk[(j + 3) & 3] = ld_bk(t, j + 3);
      bf16x8 aqN0, aqN1;
      if (j < 63) {
        aqN0 = *reinterpret_cast<const bf16x8*>(qlds + (j + 1)*1024 + l*16);
        aqN1 = *reinterpret_cast<const bf16x8*>(qlds + 65536 + (j + 1)*1024 + l*16);
      }
      qk0 = __builtin_amdgcn_mfma_f32_32x32x16_bf16(aqA0, bk[j & 3], qk0, 0, 0, 0);
      qk1 = __builtin_amdgcn_mfma_f32_32x32x16_bf16(aqA1, bk[j & 3], qk1, 0, 0, 0);
      if (j < 63) { aqA0 = aqN0; aqA1 = aqN1; }
      if (j < 61) bv[(j + 3) & 3] = ld_bv(t-1, j + 3);
      if (nf == 0) {
        pa0 = ldP(0, 7); pa1 = ldP(1, 7); pa2 = ldP(2, 7); pa3 = ldP(3, 7);
        if (w == 0) {
          lacc[0] = __builtin_amdgcn_mfma_f32_16x16x32_bf16(pa0, ones, lacc[0], 0, 0, 0);
          lacc[1] = __builtin_amdgcn_mfma_f32_16x16x32_bf16(pa1, ones, lacc[1], 0, 0, 0);
          lacc[2] = __builtin_amdgcn_mfma_f32_16x16x32_bf16(pa2, ones, lacc[2], 0, 0, 0);
          lacc[3] = __builtin_amdgcn_mfma_f32_16x16x32_bf16(pa3, ones, lacc[3], 0, 0, 0);
        }
      }
      Oacc[0][nf] = __builtin_amdgcn_mfma_f32_16x16x32_bf16(pa0, bv[j & 3], Oacc[0][nf], 0, 0, 0);
      Oacc[1][nf] = __builtin_amdgcn_mfma_f32_16x16x32_bf16(pa1, bv[j & 3], Oacc[1][nf], 0, 0, 0);
      Oacc[2][nf] = __builtin_amdgcn_mfma_f32_16x16x32_bf16(pa2, bv[j & 3], Oacc[2][nf], 0, 0, 0);
      Oacc[3][nf] = __builtin_amdgcn_mfma_f32_16x16x32_bf16(pa3, bv[j & 3], Oacc[3][nf], 0, 0, 0);
    }
  }

  // ================= epilogue: softmax(15) + PV-only =================
  BAR();
  #pragma unroll
  for (int r = 0; r < 16; ++r) {
    int qrow = (r & 3) + 8*(r >> 2) + 4*sh;
    int s    = w*32 + sl;
    {
      float p = exp2f(qk0[r] * SCL);
      int q = qrow;
      *reinterpret_cast<__bf16*>(plds + q*512 + ((s*2) ^ ((q & 7) << 4))) = (__bf16)p;
    }
    {
      float p = exp2f(qk1[r] * SCL);
      int q = 32 + qrow;
      *reinterpret_cast<__bf16*>(plds + q*512 + ((s*2) ^ ((q & 7) << 4))) = (__bf16)p;
    }
  }
  bv[0] = ld_bv(NT_-1, 0); bv[1] = ld_bv(NT_-1, 1); bv[2] = ld_bv(NT_-1, 2);
  WAITL();
  BAR();

  {
    bf16x8 pa0, pa1, pa2, pa3;
    #pragma unroll 1
    for (int ib = 0; ib < 7; ++ib) {
      #pragma unroll
      for (int j = 0; j < 8; ++j) {
        const int i = ib*8 + j;                       // 0..55
        bv[(j + 3) & 3] = ld_bv(NT_-1, i + 3);
        if (j == 0) {
          pa0 = ldP(0, ib); pa1 = ldP(1, ib); pa2 = ldP(2, ib); pa3 = ldP(3, ib);
          if (w == 0) {
            lacc[0] = __builtin_amdgcn_mfma_f32_16x16x32_bf16(pa0, ones, lacc[0], 0, 0, 0);
            lacc[1] = __builtin_amdgcn_mfma_f32_16x16x32_bf16(pa1, ones, lacc[1], 0, 0, 0);
            lacc[2] = __builtin_amdgcn_mfma_f32_16x16x32_bf16(pa2, ones, lacc[2], 0, 0, 0);
            lacc[3] = __builtin_amdgcn_mfma_f32_16x16x32_bf16(pa3, ones, lacc[3], 0, 0, 0);
          }
        }
        Oacc[0][j] = __builtin_amdgcn_mfma_f32_16x16x32_bf16(pa0, bv[j & 3], Oacc[0][j], 0, 0, 0);
        Oacc[1][j] = __builtin_amdgcn_mfma_f32_16x16x32_bf16(pa1, bv[j & 3], Oacc[1][j], 0, 0, 0);
        Oacc[2][j] = __builtin_amdgcn_mfma_f32_16x16x32_bf16(pa2, bv[j & 3], Oacc[2][j], 0, 0, 0);
        Oacc[3][j] = __builtin_amdgcn_mfma_f32_16x16x32_bf16(pa3, bv[j & 3], Oacc[3][j], 0, 0, 0);
      }
    }
    #pragma unroll
    for (int j = 56; j < 64; ++j) {                   // static tail
      const int nf = j & 7;
      if (j < 61) bv[(j + 3) & 3] = ld_bv(NT_-1, j + 3);
      if (nf == 0) {
        pa0 = ldP(0, 7); pa1 = ldP(1, 7); pa2 = ldP(2, 7); pa3 = ldP(3, 7);
        if (w == 0) {
          lacc[0] = __builtin_amdgcn_mfma_f32_16x16x32_bf16(pa0, ones, lacc[0], 0, 0, 0);
          lacc[1] = __builtin_amdgcn_mfma_f32_16x16x32_bf16(pa1, ones, lacc[1], 0, 0, 0);
          lacc[2] = __builtin_amdgcn_mfma_f32_16x16x32_bf16(pa2, ones, lacc[2], 0, 0, 0);
          lacc[3] = __builtin_amdgcn_mfma_f32_16x16x32_bf16(pa3, ones, lacc[3], 0, 0, 0);
        }
      }
      Oacc[0][nf] = __builtin_amdgcn_mfma_f32_16x16x32_bf16(pa0, bv[j & 3], Oacc[0][nf], 0, 0, 0);
      Oacc[1][nf] = __builtin_amdgcn_mfma_f32_16x16x32_bf16(pa1, bv[j & 3], Oacc[1][nf], 0, 0, 0);
      Oacc[2][nf] = __builtin_amdgcn_mfma_f32_16x16x32_bf16(pa2, bv[j & 3], Oacc[2][nf], 0, 0, 0);
      Oacc[3][nf] = __builtin_amdgcn_mfma_f32_16x16x32_bf16(pa3, bv[j & 3], Oacc[3][nf], 0, 0, 0);
    }
  }
  BAR();

  // ================= l from wave-0 ones-MFMA, write O =================
  float* lred = (float*)plds;
  if (w == 0 && lr == 0) {
    #pragma unroll
    for (int mq = 0; mq < 4; ++mq)
      #pragma unroll
      for (int j = 0; j < 4; ++j)
        lred[mq*16 + lg*4 + j] = lacc[mq][j];
  }
  WAITL();
  BAR();

  float* Ob = Og + ((size_t)b*LQ_ + (size_t)qt*BQ_)*DH_;
  #pragma unroll
  for (int mq = 0; mq < 4; ++mq)
    #pragma unroll
    for (int j = 0; j < 4; ++j) {
      int q = mq*16 + lg*4 + j;
      float rinv = 1.0f / lred[q];
      #pragma unroll
      for (int nf = 0; nf < 8; ++nf)
        Ob[(size_t)q*DH_ + w*128 + nf*16 + lr] = Oacc[mq][nf][j] * rinv;
    }
}

// ---------------- correctness-only fallback (ws too small; never expected) ----------------
__global__ void attn_naive(const float* __restrict__ Q, const float* __restrict__ S,
                           float* __restrict__ O)
{
  const int row = blockIdx.x;
  const int b = row >> 12, q = row & 4095;
  const float* qp = Q + ((size_t)b*LQ_ + q)*DH_;
  const float* sp = S + (size_t)b*LS_*DH_;
  __shared__ float qs[DH_];
  __shared__ float osum[DH_];
  __shared__ float lsum;
  for (int i = threadIdx.x; i < DH_; i += 256) { qs[i] = qp[i]; osum[i] = 0.f; }
  if (threadIdx.x == 0) lsum = 0.f;
  __syncthreads();
  float lpart = 0.f;
  for (int s0 = threadIdx.x; s0 < LS_; s0 += 256) {
    const float* sr = sp + (size_t)s0*DH_;
    float dot = 0.f;
    for (int d = 0; d < DH_; ++d) dot += qs[d]*sr[d];
    float p = __expf(dot * 0.03125f);
    lpart += p;
    for (int d = 0; d < DH_; ++d) atomicAdd(&osum[d], p*sr[d]);
  }
  atomicAdd(&lsum, lpart);
  __syncthreads();
  float rinv = 1.0f / lsum;
  float* op = O + ((size_t)b*LQ_ + q)*DH_;
  for (int i = threadIdx.x; i < DH_; i += 256) op[i] = osum[i]*rinv;
}

extern "C" void kernel_launch(void* const* d_in, const int* in_sizes, int n_in,
                              void* d_out, int out_size, void* d_ws, size_t ws_size,
                              hipStream_t stream)
{
  const float* Q = (const float*)d_in[0];
  const float* S = (const float*)d_in[1];
  float* out = (float*)d_out;

  const size_t kf_bytes = (size_t)B_*NT_*8*64*1024;   // 32 MiB
  const size_t vf_bytes = (size_t)B_*NT_*8*64*1024;   // 32 MiB
  const size_t need = kf_bytes + vf_bytes;            // 64 MiB

  if (ws_size >= need) {
    u8* Kf = (u8*)d_ws;
    u8* Vf = Kf + kf_bytes;
    cvt_kernel<<<dim3(64, 16, 4), 256, 0, stream>>>(S, Kf, Vf);
    attn_kernel<<<dim3(256), NTH, 0, stream>>>(Q, Kf, Vf, out);
  } else {
    attn_naive<<<dim3(B_*LQ_), 256, 0, stream>>>(Q, S, out);
  }
}